// Round 10
// baseline (392.258 us; speedup 1.0000x reference)
//
#include <hip/hip_runtime.h>
#include <hip/hip_bf16.h>

#define B_ 8
#define C_ 512
#define N_ 16384
#define EPSF 1e-6f
#define KSPLIT1 16
#define NTILES1 10

typedef float f32x4 __attribute__((ext_vector_type(4)));
typedef float f32x2 __attribute__((ext_vector_type(2)));
typedef short s16x8 __attribute__((ext_vector_type(8)));
typedef short s16x4 __attribute__((ext_vector_type(4)));

__device__ __forceinline__ short f2bf(float f) {
  union { float f; unsigned u; } v; v.f = f;
  unsigned r = v.u + 0x7fffu + ((v.u >> 16) & 1u);  // RNE
  return (short)(r >> 16);
}

__device__ __forceinline__ float bf2f(short s) {
  union { float f; unsigned u; } v;
  v.u = ((unsigned)(unsigned short)s) << 16;
  return v.f;
}

__device__ __forceinline__ s16x8 pack8(f32x4 a, f32x4 b) {
  s16x8 r;
  r[0] = f2bf(a[0]); r[1] = f2bf(a[1]); r[2] = f2bf(a[2]); r[3] = f2bf(a[3]);
  r[4] = f2bf(b[0]); r[5] = f2bf(b[1]); r[6] = f2bf(b[2]); r[7] = f2bf(b[3]);
  return r;
}

__device__ __forceinline__ void mfma16(f32x4& d, s16x8 a, s16x8 b) {
  asm("v_mfma_f32_16x16x32_bf16 %0, %1, %2, %0" : "+v"(d) : "v"(a), "v"(b));
}

// async global->LDS, 16B per lane, LDS dest = wave-uniform base + lane*16
#define GLOAD16(gp, lp)                                                        \
  __builtin_amdgcn_global_load_lds(                                            \
      (const __attribute__((address_space(1))) unsigned int*)(gp),             \
      (__attribute__((address_space(3))) unsigned int*)(lp), 16, 0, 0)

// ---------------------------------------------------------------------------
// K1 (fused): per block = (b, 64-n slab, all 512 c). One HBM x-pass.
// Register-stash version: thread keeps its 32 rows x 4 n as bf16 in VGPRs
// (no 64KB LDS tile, no LDS transpose). Phase-1 mapping == phase-2 mapping
// (nq=t&15, cs=t>>4): reads 256B-coalesced, W writes 128B lines.
__global__ __launch_bounds__(256) void k_prep4(const float* __restrict__ x,
                                               float* __restrict__ csum,
                                               float* __restrict__ normv,
                                               short* __restrict__ W,
                                               short* __restrict__ QnT,
                                               float* __restrict__ tpart) {
  __shared__ f32x4 pss[4][16], pcs[4][16];   // [wave][nq]
  __shared__ float invs[64], rss[64], t2s[64];
  __shared__ float tps[512];
  int blk = blockIdx.x;
  int nslab = blk & 255, b = blk >> 8;
  int n0g = nslab * 64;
  int t = threadIdx.x, nq = t & 15, cs = t >> 4;   // cs 0..15 (32-row segs)
  int w = t >> 6, lq = t & 63;

  // ---- phase 1: stream 32 rows, stats + bf16 stash in registers
  const float* xp = x + ((size_t)b * C_ + cs * 32) * N_ + n0g + nq * 4;
  s16x4 bv[32];
  f32x4 ss = {0.f, 0.f, 0.f, 0.f}, sc = {0.f, 0.f, 0.f, 0.f};
#pragma unroll
  for (int r = 0; r < 32; ++r) {
    f32x4 v = *(const f32x4*)(xp + (size_t)r * N_);
    ss += v * v;
    sc += v;
    s16x4 q;
    q[0] = f2bf(v[0]); q[1] = f2bf(v[1]); q[2] = f2bf(v[2]); q[3] = f2bf(v[3]);
    bv[r] = q;
  }
  // reduce over cs within wave (cs low bits = lane bits 4..5)
#pragma unroll
  for (int j = 0; j < 4; ++j) {
    float a = ss[j], c = sc[j];
    a += __shfl_xor(a, 16, 64); c += __shfl_xor(c, 16, 64);
    a += __shfl_xor(a, 32, 64); c += __shfl_xor(c, 32, 64);
    ss[j] = a; sc[j] = c;
  }
  if (lq < 16) { pss[w][nq] = ss; pcs[w][nq] = sc; }
  __syncthreads();
  if (t < 64) {
    int q = t >> 2, j = t & 3;
    float s = 0.f, c = 0.f;
#pragma unroll
    for (int k2 = 0; k2 < 4; ++k2) { s += pss[k2][q][j]; c += pcs[k2][q][j]; }
    float nr = sqrtf(s);
    float iv = 1.0f / nr;
    invs[t] = iv;
    rss[t] = sqrtf(iv);
    t2s[t] = fmaf(c, iv, EPSF);
    csum[(size_t)b * N_ + n0g + t] = c;
    normv[(size_t)b * N_ + n0g + t] = nr;
  }
  __syncthreads();

  // ---- phase 2: from registers -> W, QnT, tailor partials
  float ivl[4], rsl[4], t2l[4];
#pragma unroll
  for (int j = 0; j < 4; ++j) {
    ivl[j] = invs[nq * 4 + j];
    rsl[j] = rss[nq * 4 + j];
    t2l[j] = t2s[nq * 4 + j];
  }
  short* Wp = W + ((size_t)b * C_ + cs * 32) * N_ + n0g + nq * 4;
  short* Qp = QnT + ((size_t)b * N_ + n0g + nq * 4) * C_ + cs * 32;
#pragma unroll
  for (int g = 0; g < 4; ++g) {
    s16x8 qcol[4];
#pragma unroll
    for (int r2 = 0; r2 < 8; ++r2) {
      int r = g * 8 + r2;
      s16x4 xv = bv[r];
      s16x4 wv;
      float tp = 0.f;
#pragma unroll
      for (int j = 0; j < 4; ++j) {
        float xf = bf2f(xv[j]);
        wv[j] = f2bf(xf * rsl[j]);
        float q = xf * ivl[j];
        qcol[j][r2] = f2bf(q);
        tp = fmaf(q, t2l[j], tp);
      }
      *(s16x4*)(Wp + (size_t)r * N_) = wv;     // 16 nq-lanes x 8B = 128B line
      tp += __shfl_xor(tp, 1, 64);
      tp += __shfl_xor(tp, 2, 64);
      tp += __shfl_xor(tp, 4, 64);
      tp += __shfl_xor(tp, 8, 64);
      if (nq == 0) tps[cs * 32 + r] = tp;
    }
#pragma unroll
    for (int j = 0; j < 4; ++j)
      *(s16x8*)(Qp + (size_t)j * C_ + g * 8) = qcol[j];  // 16B; g-loop fills line
  }
  __syncthreads();
  // coalesced tailor-partial write: 512 floats
  *(f32x2*)&tpart[((size_t)b * 256 + nslab) * 512 + t * 2] = *(f32x2*)&tps[t * 2];
}

// K1b: finalize tailor over 256 nslab partials (layout [b][nslab][c])
__global__ __launch_bounds__(256) void k_tailor2(const float* __restrict__ tpart,
                                                 float* __restrict__ tail) {
  int i = blockIdx.x * 256 + threadIdx.x;  // 0..4095 = (b,c)
  int b = i >> 9, c = i & 511;
  const float* p = tpart + (size_t)b * 256 * 512 + c;
  float s = 0.f;
#pragma unroll 8
  for (int ns = 0; ns < 256; ++ns) s += p[(size_t)ns * 512];
  tail[i] = 1.0f / ((float)N_ + s);
}

// ---------------------------------------------------------------------------
// K3: GEMM1 split-K, SYMMETRIC: only 10 upper-tri 128x128 tile-pairs.
__global__ __launch_bounds__(256) void k_gemm1(const short* __restrict__ W,
                                               float* __restrict__ matP) {
  __shared__ __align__(16) short As[8192];
  __shared__ __align__(16) short Bs[8192];
  const int TI[NTILES1] = {0, 0, 0, 0, 1, 1, 1, 2, 2, 3};
  const int TJ[NTILES1] = {0, 1, 2, 3, 1, 2, 3, 2, 3, 3};
  int bid = blockIdx.x;
  int ks = bid & 15; bid >>= 4;
  int tt = bid % NTILES1;
  int b = bid / NTILES1;
  int mt = TI[tt], nt = TJ[tt];

  int t = threadIdx.x, lane = t & 63, w = t >> 6;
  int wr = w >> 1, wc = w & 1;
  int prow0 = lane >> 3;
  int swz = ((lane & 7) * 16) ^ (prow0 << 4);

  const short* Wb = W + (size_t)b * C_ * N_;
  const char* gA[4]; const char* gB[4];
  short* lA[4]; short* lB[4];
#pragma unroll
  for (int cc = 0; cc < 4; ++cc) {
    int q = w * 4 + cc;
    int row = q * 8 + prow0;
    gA[cc] = (const char*)(Wb + (size_t)(mt * 128 + row) * N_) + swz;
    gB[cc] = (const char*)(Wb + (size_t)(nt * 128 + row) * N_) + swz;
    lA[cc] = &As[q * 512];
    lB[cc] = &Bs[q * 512];
  }

  f32x4 acc[4][4];
#pragma unroll
  for (int i = 0; i < 4; ++i)
#pragma unroll
    for (int j = 0; j < 4; ++j) acc[i][j] = f32x4{0.f, 0.f, 0.f, 0.f};

  int kbeg = ks * (N_ / KSPLIT1);
  for (int kk = 0; kk < N_ / KSPLIT1; kk += 64) {
    __syncthreads();
    size_t koff = (size_t)(kbeg + kk) * 2;
#pragma unroll
    for (int cc = 0; cc < 4; ++cc) GLOAD16(gA[cc] + koff, lA[cc]);
#pragma unroll
    for (int cc = 0; cc < 4; ++cc) GLOAD16(gB[cc] + koff, lB[cc]);
    __syncthreads();
#pragma unroll
    for (int h = 0; h < 2; ++h) {
      int kb = h * 64 + (lane >> 4) * 16;
      s16x8 af[4], bf[4];
#pragma unroll
      for (int mi = 0; mi < 4; ++mi) {
        int row = wr * 64 + mi * 16 + (lane & 15);
        af[mi] = *(const s16x8*)((const char*)As + row * 128 + (kb ^ ((row & 7) << 4)));
      }
#pragma unroll
      for (int ni = 0; ni < 4; ++ni) {
        int row = wc * 64 + ni * 16 + (lane & 15);
        bf[ni] = *(const s16x8*)((const char*)Bs + row * 128 + (kb ^ ((row & 7) << 4)));
      }
#pragma unroll
      for (int mi = 0; mi < 4; ++mi)
#pragma unroll
        for (int ni = 0; ni < 4; ++ni) mfma16(acc[mi][ni], af[mi], bf[ni]);
    }
  }
  asm volatile("s_nop 7\n\ts_nop 7\n\ts_nop 7" ::);
  float* mp = matP + (((size_t)ks * B_ + b) * NTILES1 + tt) * 16384;
#pragma unroll
  for (int mi = 0; mi < 4; ++mi)
#pragma unroll
    for (int ni = 0; ni < 4; ++ni) {
      int col = wc * 64 + ni * 16 + (lane & 15);
#pragma unroll
      for (int r = 0; r < 4; ++r) {
        int row = wr * 64 + mi * 16 + (lane >> 4) * 4 + r;
        mp[(size_t)row * 128 + col] = acc[mi][ni][r];
      }
    }
}

// K3b: sum split-K partials, convert to bf16, mirror into full matF
__global__ __launch_bounds__(256) void k_redsum2(const float* __restrict__ matP,
                                                 short* __restrict__ matF) {
  const int TI[NTILES1] = {0, 0, 0, 0, 1, 1, 1, 2, 2, 3};
  const int TJ[NTILES1] = {0, 1, 2, 3, 1, 2, 3, 2, 3, 3};
  size_t idx = (size_t)blockIdx.x * 256 + threadIdx.x;
  int b = (int)(idx / (NTILES1 * 16384));
  int rem = (int)(idx % (NTILES1 * 16384));
  int tt = rem >> 14;
  int e = rem & 16383;
  int rowl = e >> 7, col = e & 127;
  float s = 0.f;
#pragma unroll
  for (int ks = 0; ks < KSPLIT1; ++ks)
    s += matP[(((size_t)ks * B_ + b) * NTILES1 + tt) * 16384 + e];
  short v = f2bf(s);
  int ti = TI[tt], tj = TJ[tt];
  short* mb = matF + (size_t)b * C_ * C_;
  mb[(size_t)(ti * 128 + rowl) * C_ + tj * 128 + col] = v;
  if (ti != tj) mb[(size_t)(tj * 128 + col) * C_ + ti * 128 + rowl] = v;
}

// ---------------------------------------------------------------------------
// K4: GEMM2 + epilogue, x-read-free (residual from staged Qn tile; round-8
// proven). 512 thr / 8 waves, 128x128 tile, BK=64 dbuf, counted vmcnt(4).
__global__ __launch_bounds__(512, 4) void k_gemm2(const short* __restrict__ matF,
                                                  const short* __restrict__ QnT,
                                                  const float* __restrict__ csum,
                                                  const float* __restrict__ normv,
                                                  const float* __restrict__ tail,
                                                  const float* __restrict__ gamma,
                                                  float* __restrict__ out) {
  __shared__ __align__(16) short As[2][8192];
  __shared__ __align__(16) short Bs[2][8192];
  int bid = blockIdx.x;
  int nt = bid & 127; bid >>= 7;
  int mt = bid & 3; bid >>= 2;
  int b = bid;

  int t = threadIdx.x, lane = t & 63, w = t >> 6;  // 8 waves
  int wr = w >> 2, wc = w & 3;                     // 2(m) x 4(n) wave grid
  int prow0 = lane >> 3;
  int swz = ((lane & 7) * 16) ^ (prow0 << 4);

  const char* gA[2]; const char* gB[2];
  int lofs[2];
#pragma unroll
  for (int cc = 0; cc < 2; ++cc) {
    int q = w * 2 + cc;
    int row = q * 8 + prow0;
    gA[cc] = (const char*)(matF + ((size_t)b * C_ + mt * 128 + row) * C_) + swz;
    gB[cc] = (const char*)(QnT + ((size_t)b * N_ + nt * 128 + row) * C_) + swz;
    lofs[cc] = q * 512;
  }

  f32x4 acc[4][2];
  float xres[4][2][4];   // captured residual q-values (bf16 widened)
#pragma unroll
  for (int i = 0; i < 4; ++i)
#pragma unroll
    for (int j = 0; j < 2; ++j) {
      acc[i][j] = f32x4{0.f, 0.f, 0.f, 0.f};
#pragma unroll
      for (int r = 0; r < 4; ++r) xres[i][j][r] = 0.f;
    }

#define STG2(pb, kof)                                                          \
  do {                                                                         \
    _Pragma("unroll")                                                          \
    for (int cc = 0; cc < 2; ++cc) GLOAD16(gA[cc] + (kof), &As[pb][lofs[cc]]); \
    _Pragma("unroll")                                                          \
    for (int cc = 0; cc < 2; ++cc) GLOAD16(gB[cc] + (kof), &Bs[pb][lofs[cc]]); \
  } while (0)

  STG2(0, 0);
  int ctk = mt * 2 + wr;   // iteration whose Bs tile holds this wave's residuals
#pragma unroll
  for (int tk = 0; tk < 8; ++tk) {
    if (tk < 7) {
      STG2((tk + 1) & 1, (size_t)(tk + 1) * 128);
      asm volatile("s_waitcnt vmcnt(4)" ::: "memory");
    } else {
      asm volatile("s_waitcnt vmcnt(0)" ::: "memory");
    }
    asm volatile("s_barrier" ::: "memory");
    const char* pA = (const char*)As[tk & 1];
    const char* pB = (const char*)Bs[tk & 1];
#pragma unroll
    for (int h = 0; h < 2; ++h) {
      int kb = h * 64 + (lane >> 4) * 16;
      s16x8 af[4], bf[2];
#pragma unroll
      for (int mi = 0; mi < 4; ++mi) {
        int row = wr * 64 + mi * 16 + (lane & 15);
        af[mi] = *(const s16x8*)(pA + row * 128 + (kb ^ ((row & 7) << 4)));
      }
#pragma unroll
      for (int ni = 0; ni < 2; ++ni) {
        int row = wc * 32 + ni * 16 + (lane & 15);
        bf[ni] = *(const s16x8*)(pB + row * 128 + (kb ^ ((row & 7) << 4)));
      }
#pragma unroll
      for (int mi = 0; mi < 4; ++mi)
#pragma unroll
        for (int ni = 0; ni < 2; ++ni) mfma16(acc[mi][ni], af[mi], bf[ni]);
    }
    // residual capture: Bs row = output col (n), k = output row's local c
    if (tk == ctk) {
#pragma unroll
      for (int mi = 0; mi < 4; ++mi)
#pragma unroll
        for (int r = 0; r < 4; ++r) {
          int kbyte = (mi * 16 + (lane >> 4) * 4 + r) * 2;
#pragma unroll
          for (int ni = 0; ni < 2; ++ni) {
            int row = wc * 32 + ni * 16 + (lane & 15);
            short q = *(const short*)(pB + row * 128 + (kbyte ^ ((row & 7) << 4)));
            xres[mi][ni][r] = bf2f(q);
          }
        }
      asm volatile("s_waitcnt lgkmcnt(0)" ::: "memory");  // latch before overwrite
    }
    asm volatile("s_barrier" ::: "memory");
  }
#undef STG2
  asm volatile("s_nop 7\n\ts_nop 7\n\ts_nop 7" ::);
  float g = gamma[0];
#pragma unroll
  for (int mi = 0; mi < 4; ++mi)
#pragma unroll
    for (int ni = 0; ni < 2; ++ni) {
      int coln = nt * 128 + wc * 32 + ni * 16 + (lane & 15);
      float vs = csum[(size_t)b * N_ + coln];
      float nr = normv[(size_t)b * N_ + coln];
#pragma unroll
      for (int r = 0; r < 4; ++r) {
        int rowg = mt * 128 + wr * 64 + mi * 16 + (lane >> 4) * 4 + r;
        float ts = tail[b * C_ + rowg];
        size_t off = ((size_t)b * C_ + rowg) * N_ + coln;
        out[off] = xres[mi][ni][r] * nr + g * ((vs + acc[mi][ni][r]) * ts);
      }
    }
}

// ===========================================================================
// Tier B fallback (round-1 proven path, used only if ws is small)
// ===========================================================================
__global__ __launch_bounds__(256) void k_stats(const float* __restrict__ x,
                                               float* __restrict__ inv,
                                               float* __restrict__ csum) {
  __shared__ f32x4 ssm[4][64];
  __shared__ f32x4 csm[4][64];
  int t = threadIdx.x, nq = t & 63, cs = t >> 6;
  int g0 = blockIdx.x * 256 + nq * 4;
  int b = g0 >> 14;
  int n = g0 & (N_ - 1);
  const float* p = x + ((size_t)b * C_ + cs * 128) * N_ + n;
  f32x4 ss = {0.f, 0.f, 0.f, 0.f}, sc = {0.f, 0.f, 0.f, 0.f};
  for (int c = 0; c < 128; ++c) {
    f32x4 v = *(const f32x4*)(p + (size_t)c * N_);
    ss += v * v;
    sc += v;
  }
  ssm[cs][nq] = ss; csm[cs][nq] = sc;
  __syncthreads();
  if (t < 64) {
    f32x4 s1 = ssm[0][t] + ssm[1][t] + ssm[2][t] + ssm[3][t];
    f32x4 c1 = csm[0][t] + csm[1][t] + csm[2][t] + csm[3][t];
    f32x4 r;
#pragma unroll
    for (int j = 0; j < 4; ++j) r[j] = 1.0f / sqrtf(s1[j]);
    int g = blockIdx.x * 256 + t * 4;
    *(f32x4*)(inv + g) = r;
    *(f32x4*)(csum + g) = c1;
  }
}

__global__ __launch_bounds__(256) void k_tailor_fb(const float* __restrict__ x,
                                                   const float* __restrict__ inv,
                                                   const float* __restrict__ csum,
                                                   float* __restrict__ tail) {
  int b = blockIdx.x >> 9;
  const float* row = x + (size_t)blockIdx.x * N_;
  const float* ib = inv + b * N_;
  const float* cb = csum + b * N_;
  int t = threadIdx.x;
  float acc = 0.f;
  for (int i = t * 4; i < N_; i += 1024) {
    f32x4 v = *(const f32x4*)(row + i);
    f32x4 iv = *(const f32x4*)(ib + i);
    f32x4 cv = *(const f32x4*)(cb + i);
#pragma unroll
    for (int j = 0; j < 4; ++j) acc += v[j] * (iv[j] * fmaf(iv[j], cv[j], EPSF));
  }
#pragma unroll
  for (int off = 32; off > 0; off >>= 1) acc += __shfl_down(acc, off, 64);
  __shared__ float red[4];
  if ((t & 63) == 0) red[t >> 6] = acc;
  __syncthreads();
  if (t == 0) tail[blockIdx.x] = 1.0f / ((float)N_ + red[0] + red[1] + red[2] + red[3]);
}

__global__ __launch_bounds__(256) void k_gemm1_fb(const float* __restrict__ x,
                                                  const float* __restrict__ inv,
                                                  float* __restrict__ mpart,
                                                  int ksplit) {
  __shared__ short As[128 * 40];
  __shared__ short Bs[128 * 40];
  int bid = blockIdx.x;
  int ks = bid % ksplit; bid /= ksplit;
  int nt = bid & 3; bid >>= 2;
  int mt = bid & 3; bid >>= 2;
  int b = bid;
  int kch = N_ / ksplit;
  int kbeg = ks * kch, kend = kbeg + kch;
  int t = threadIdx.x, lane = t & 63, w = t >> 6, wr = w >> 1, wc = w & 1;
  int srow = t >> 1, skh = t & 1;
  const float* xb = x + (size_t)b * C_ * N_;
  const float* ga = xb + (size_t)(mt * 128 + srow) * N_ + skh * 16;
  const float* gb = xb + (size_t)(nt * 128 + srow) * N_ + skh * 16;
  const float* gi = inv + b * N_ + skh * 16;
  f32x4 acc[4][4];
#pragma unroll
  for (int i = 0; i < 4; ++i)
#pragma unroll
    for (int j = 0; j < 4; ++j) acc[i][j] = f32x4{0.f, 0.f, 0.f, 0.f};
  int ldsw = srow * 40 + skh * 16;
  int lra = (wr * 64 + (lane & 15)) * 40 + (lane >> 4) * 8;
  int lrb = (wc * 64 + (lane & 15)) * 40 + (lane >> 4) * 8;
  for (int kk = kbeg; kk < kend; kk += 32) {
    __syncthreads();
    {
      f32x4 a0 = *(const f32x4*)(ga + kk), a1 = *(const f32x4*)(ga + kk + 4);
      f32x4 a2 = *(const f32x4*)(ga + kk + 8), a3 = *(const f32x4*)(ga + kk + 12);
      f32x4 b0 = *(const f32x4*)(gb + kk), b1 = *(const f32x4*)(gb + kk + 4);
      f32x4 b2 = *(const f32x4*)(gb + kk + 8), b3 = *(const f32x4*)(gb + kk + 12);
      f32x4 i0 = *(const f32x4*)(gi + kk), i1 = *(const f32x4*)(gi + kk + 4);
      f32x4 i2 = *(const f32x4*)(gi + kk + 8), i3 = *(const f32x4*)(gi + kk + 12);
      *(s16x8*)&As[ldsw] = pack8(a0, a1);
      *(s16x8*)&As[ldsw + 8] = pack8(a2, a3);
      *(s16x8*)&Bs[ldsw] = pack8(b0 * i0, b1 * i1);
      *(s16x8*)&Bs[ldsw + 8] = pack8(b2 * i2, b3 * i3);
    }
    __syncthreads();
    s16x8 af[4], bf[4];
#pragma unroll
    for (int mi = 0; mi < 4; ++mi) af[mi] = *(const s16x8*)&As[lra + mi * 16 * 40];
#pragma unroll
    for (int ni = 0; ni < 4; ++ni) bf[ni] = *(const s16x8*)&Bs[lrb + ni * 16 * 40];
#pragma unroll
    for (int mi = 0; mi < 4; ++mi)
#pragma unroll
      for (int ni = 0; ni < 4; ++ni) mfma16(acc[mi][ni], af[mi], bf[ni]);
  }
  asm volatile("s_nop 7\n\ts_nop 7\n\ts_nop 7" ::);
  float* mp = mpart + ((size_t)ks * B_ + b) * C_ * C_;
#pragma unroll
  for (int mi = 0; mi < 4; ++mi)
#pragma unroll
    for (int ni = 0; ni < 4; ++ni) {
      int col = nt * 128 + wc * 64 + ni * 16 + (lane & 15);
#pragma unroll
      for (int r = 0; r < 4; ++r) {
        int rowg = mt * 128 + wr * 64 + mi * 16 + (lane >> 4) * 4 + r;
        mp[(size_t)rowg * C_ + col] = acc[mi][ni][r];
      }
    }
}

__global__ __launch_bounds__(256) void k_reduce_fb(const float* __restrict__ mpart,
                                                   float* __restrict__ mfull,
                                                   int ksplit) {
  size_t i = (size_t)blockIdx.x * 256 + threadIdx.x;
  float s = 0.f;
  for (int k = 0; k < ksplit; ++k) s += mpart[(size_t)k * (B_ * C_ * C_) + i];
  mfull[i] = s;
}

__global__ __launch_bounds__(256) void k_gemm2_fb(const float* __restrict__ x,
                                                  const float* __restrict__ mat,
                                                  const float* __restrict__ inv,
                                                  const float* __restrict__ csum,
                                                  const float* __restrict__ tail,
                                                  const float* __restrict__ gamma,
                                                  float* __restrict__ out) {
  __shared__ short As[128 * 40];
  __shared__ short Bs[128 * 40];
  int bid = blockIdx.x;
  int nt = bid & 127; bid >>= 7;
  int mt = bid & 3; bid >>= 2;
  int b = bid;
  int t = threadIdx.x, lane = t & 63, w = t >> 6, wr = w >> 1, wc = w & 1;
  int srow = t >> 1, skh = t & 1;
  const float* gA = mat + ((size_t)b * C_ + mt * 128 + srow) * C_ + skh * 16;
  int kb = t >> 5, cbl = t & 31;
  int k0l = kb * 4, n0 = cbl * 4;
  const float* xb = x + (size_t)b * C_ * N_;
  const float* gB = xb + (size_t)k0l * N_ + nt * 128 + n0;
  f32x4 ivn = *(const f32x4*)(inv + b * N_ + nt * 128 + n0);
  f32x4 acc[4][4];
#pragma unroll
  for (int i = 0; i < 4; ++i)
#pragma unroll
    for (int j = 0; j < 4; ++j) acc[i][j] = f32x4{0.f, 0.f, 0.f, 0.f};
  int ldsw = srow * 40 + skh * 16;
  int lra = (wr * 64 + (lane & 15)) * 40 + (lane >> 4) * 8;
  int lrb = (wc * 64 + (lane & 15)) * 40 + (lane >> 4) * 8;
  for (int kk = 0; kk < C_; kk += 32) {
    __syncthreads();
    {
      f32x4 a0 = *(const f32x4*)(gA + kk), a1 = *(const f32x4*)(gA + kk + 4);
      f32x4 a2 = *(const f32x4*)(gA + kk + 8), a3 = *(const f32x4*)(gA + kk + 12);
      *(s16x8*)&As[ldsw] = pack8(a0, a1);
      *(s16x8*)&As[ldsw + 8] = pack8(a2, a3);
      const float* pB = gB + (size_t)kk * N_;
      f32x4 v0 = *(const f32x4*)(pB);
      f32x4 v1 = *(const f32x4*)(pB + N_);
      f32x4 v2 = *(const f32x4*)(pB + 2 * N_);
      f32x4 v3 = *(const f32x4*)(pB + 3 * N_);
#pragma unroll
      for (int cc = 0; cc < 4; ++cc) {
        s16x4 q;
        q[0] = f2bf(v0[cc] * ivn[cc]);
        q[1] = f2bf(v1[cc] * ivn[cc]);
        q[2] = f2bf(v2[cc] * ivn[cc]);
        q[3] = f2bf(v3[cc] * ivn[cc]);
        *(s16x4*)&Bs[(n0 + cc) * 40 + k0l] = q;
      }
    }
    __syncthreads();
    s16x8 af[4], bf[4];
#pragma unroll
    for (int mi = 0; mi < 4; ++mi) af[mi] = *(const s16x8*)&As[lra + mi * 16 * 40];
#pragma unroll
    for (int ni = 0; ni < 4; ++ni) bf[ni] = *(const s16x8*)&Bs[lrb + ni * 16 * 40];
#pragma unroll
    for (int mi = 0; mi < 4; ++mi)
#pragma unroll
      for (int ni = 0; ni < 4; ++ni) mfma16(acc[mi][ni], af[mi], bf[ni]);
  }
  asm volatile("s_nop 7\n\ts_nop 7\n\ts_nop 7" ::);
  float g = gamma[0];
#pragma unroll
  for (int mi = 0; mi < 4; ++mi)
#pragma unroll
    for (int ni = 0; ni < 4; ++ni) {
      int coln = nt * 128 + wc * 64 + ni * 16 + (lane & 15);
      float vs = csum[b * N_ + coln];
#pragma unroll
      for (int r = 0; r < 4; ++r) {
        int rowg = mt * 128 + wr * 64 + mi * 16 + (lane >> 4) * 4 + r;
        float ts = tail[b * C_ + rowg];
        size_t off = ((size_t)b * C_ + rowg) * N_ + coln;
        out[off] = x[off] + g * ((vs + acc[mi][ni][r]) * ts);
      }
    }
}

// ---------------------------------------------------------------------------
extern "C" void kernel_launch(void* const* d_in, const int* in_sizes, int n_in,
                              void* d_out, int out_size, void* d_ws, size_t ws_size,
                              hipStream_t stream) {
  const float* x = (const float*)d_in[0];
  const float* gamma = (const float*)d_in[1];
  float* out = (float*)d_out;
  float* wsf = (float*)d_ws;

  // Tier A ws layout (floats): csum[131072] norm[131072] tail[4096]
  //   matF[1048576 slots = 2M bf16] QnT[33554432 slots = 64M bf16]
  const size_t needA = 139476992ull;
  if (ws_size >= needA) {
    float* csum = wsf;
    float* normv = wsf + 131072;
    float* tail = wsf + 262144;
    short* matF = (short*)(wsf + 266240);
    short* QnT = (short*)(wsf + 1314816);
    // d_out scratch: W bf16 [0,128MB) | matP fp32 [128MB,208MB) | tpart [208MB,212MB)
    short* W = (short*)d_out;
    float* matP = (float*)d_out + 33554432ull;
    float* tpart = (float*)d_out + 54525952ull;

    k_prep4<<<2048, 256, 0, stream>>>(x, csum, normv, W, QnT, tpart);
    k_tailor2<<<16, 256, 0, stream>>>(tpart, tail);
    k_gemm1<<<B_ * NTILES1 * KSPLIT1, 256, 0, stream>>>(W, matP);
    k_redsum2<<<(B_ * NTILES1 * 16384) / 256, 256, 0, stream>>>(matP, matF);
    k_gemm2<<<4096, 512, 0, stream>>>(matF, QnT, csum, normv, tail, gamma, out);
  } else {
    // Tier B: round-1 proven path
    float* inv = wsf;
    float* csum = wsf + 131072;
    float* tail = wsf + 262144;
    float* matP = wsf + 266240;
    int ksplit = (ws_size >= 43008000ull) ? 4 : 1;
    float* matF = (ksplit > 1) ? (matP + (size_t)ksplit * 2097152) : matP;

    k_stats<<<512, 256, 0, stream>>>(x, inv, csum);
    k_tailor_fb<<<B_ * C_, 256, 0, stream>>>(x, inv, csum, tail);
    k_gemm1_fb<<<B_ * 16 * ksplit, 256, 0, stream>>>(x, inv, matP, ksplit);
    if (ksplit > 1) k_reduce_fb<<<8192, 256, 0, stream>>>(matP, matF, ksplit);
    k_gemm2_fb<<<B_ * 4 * 128, 256, 0, stream>>>(x, matF, inv, csum, tail, gamma, out);
  }
}

// Round 11
// 330.844 us; speedup vs baseline: 1.1856x; 1.1856x over previous
//
#include <hip/hip_runtime.h>
#include <hip/hip_bf16.h>

#define B_ 8
#define C_ 512
#define N_ 16384
#define EPSF 1e-6f
#define KSPLIT1 16
#define NTILES1 10

typedef float f32x4 __attribute__((ext_vector_type(4)));
typedef short s16x8 __attribute__((ext_vector_type(8)));
typedef short s16x4 __attribute__((ext_vector_type(4)));

__device__ __forceinline__ short f2bf(float f) {
  union { float f; unsigned u; } v; v.f = f;
  unsigned r = v.u + 0x7fffu + ((v.u >> 16) & 1u);  // RNE
  return (short)(r >> 16);
}

__device__ __forceinline__ float bf2f(short s) {
  union { float f; unsigned u; } v;
  v.u = ((unsigned)(unsigned short)s) << 16;
  return v.f;
}

__device__ __forceinline__ s16x8 pack8(f32x4 a, f32x4 b) {
  s16x8 r;
  r[0] = f2bf(a[0]); r[1] = f2bf(a[1]); r[2] = f2bf(a[2]); r[3] = f2bf(a[3]);
  r[4] = f2bf(b[0]); r[5] = f2bf(b[1]); r[6] = f2bf(b[2]); r[7] = f2bf(b[3]);
  return r;
}

__device__ __forceinline__ void mfma16(f32x4& d, s16x8 a, s16x8 b) {
  asm("v_mfma_f32_16x16x32_bf16 %0, %1, %2, %0" : "+v"(d) : "v"(a), "v"(b));
}

// async global->LDS, 16B per lane, LDS dest = wave-uniform base + lane*16
#define GLOAD16(gp, lp)                                                        \
  __builtin_amdgcn_global_load_lds(                                            \
      (const __attribute__((address_space(1))) unsigned int*)(gp),             \
      (__attribute__((address_space(3))) unsigned int*)(lp), 16, 0, 0)

// ---------------------------------------------------------------------------
// K1 (fused): per block = (b, 64-n slab, all 512 c). One HBM x-pass.
// prep2's proven memory patterns, 512 threads (2 blk/CU -> 16 waves/CU).
__global__ __launch_bounds__(512) void k_prep5(const float* __restrict__ x,
                                               float* __restrict__ csum,
                                               float* __restrict__ normv,
                                               short* __restrict__ W,
                                               short* __restrict__ QnT,
                                               float* __restrict__ tpart) {
  __shared__ short xbf[512 * 64];   // [c][n] bf16, 64KB
  __shared__ f32x4 pss[8][16], pcs[8][16];
  __shared__ float invs[64], rss[64], t2s[64];
  int blk = blockIdx.x;
  int nslab = blk & 255, b = blk >> 8;
  int n0g = nslab * 64;
  int t = threadIdx.x;

  // ---- phase 1: thread = (nq, cs) = 16 n-quads x 32 c-segs of 16 rows
  {
    int nq = t & 15, cs = t >> 4;
    const float* xp = x + ((size_t)b * C_ + cs * 16) * N_ + n0g + nq * 4;
    short* lp = &xbf[(cs * 16) * 64 + nq * 4];
    f32x4 ss = {0.f, 0.f, 0.f, 0.f}, sc = {0.f, 0.f, 0.f, 0.f};
#pragma unroll
    for (int r = 0; r < 16; ++r) {
      f32x4 v = *(const f32x4*)(xp + (size_t)r * N_);
      ss += v * v;
      sc += v;
      s16x4 bv;
      bv[0] = f2bf(v[0]); bv[1] = f2bf(v[1]); bv[2] = f2bf(v[2]); bv[3] = f2bf(v[3]);
      *(s16x4*)(lp + r * 64) = bv;
    }
    // reduce the 4 cs-segs within each wave (cs low bits = lane bits 4..5)
#pragma unroll
    for (int j = 0; j < 4; ++j) {
      float a = ss[j], c = sc[j];
      a += __shfl_xor(a, 16, 64); c += __shfl_xor(c, 16, 64);
      a += __shfl_xor(a, 32, 64); c += __shfl_xor(c, 32, 64);
      ss[j] = a; sc[j] = c;
    }
    int w = t >> 6;
    if ((t & 63) < 16) { pss[w][nq] = ss; pcs[w][nq] = sc; }
  }
  __syncthreads();
  if (t < 64) {
    int q = t >> 2, j = t & 3;
    float s = 0.f, c = 0.f;
#pragma unroll
    for (int k = 0; k < 8; ++k) { s += pss[k][q][j]; c += pcs[k][q][j]; }
    float nr = sqrtf(s);
    float iv = 1.0f / nr;
    invs[t] = iv;
    rss[t] = sqrtf(iv);
    t2s[t] = fmaf(c, iv, EPSF);
    csum[(size_t)b * N_ + n0g + t] = c;
    normv[(size_t)b * N_ + n0g + t] = nr;
  }
  __syncthreads();

  // ---- phase 2: thread = (ng, cg) = 8 n-octs x 64 c-chunks of 8
  int ng = t & 7, cg = t >> 3;
  int nl = ng * 8;
  float ivl[8], rsl[8], t2l[8];
#pragma unroll
  for (int j = 0; j < 8; ++j) {
    ivl[j] = invs[nl + j];
    rsl[j] = rss[nl + j];
    t2l[j] = t2s[nl + j];
  }
  int c0 = cg * 8;
  s16x8 qcol[8];
  float tpc[8];
#pragma unroll
  for (int i = 0; i < 8; ++i) {
    s16x8 xv = *(const s16x8*)&xbf[(c0 + i) * 64 + nl];
    s16x8 wv;
    float tp = 0.f;
#pragma unroll
    for (int j = 0; j < 8; ++j) {
      float xf = bf2f(xv[j]);
      wv[j] = f2bf(xf * rsl[j]);
      float q = xf * ivl[j];
      qcol[j][i] = f2bf(q);
      tp = fmaf(q, t2l[j], tp);
    }
    *(s16x8*)(W + ((size_t)b * C_ + c0 + i) * N_ + n0g + nl) = wv;
    tpc[i] = tp;
  }
#pragma unroll
  for (int j = 0; j < 8; ++j)
    *(s16x8*)(QnT + ((size_t)b * N_ + n0g + nl + j) * C_ + c0) = qcol[j];
#pragma unroll
  for (int i = 0; i < 8; ++i) {
    float v2 = tpc[i];
    v2 += __shfl_xor(v2, 1, 64);
    v2 += __shfl_xor(v2, 2, 64);
    v2 += __shfl_xor(v2, 4, 64);
    if (ng == 0) tpart[((size_t)b * 256 + nslab) * 512 + c0 + i] = v2;
  }
}

// K1b: finalize tailor over 256 nslab partials (layout [b][nslab][c])
__global__ __launch_bounds__(256) void k_tailor2(const float* __restrict__ tpart,
                                                 float* __restrict__ tail) {
  int i = blockIdx.x * 256 + threadIdx.x;  // 0..4095 = (b,c)
  int b = i >> 9, c = i & 511;
  const float* p = tpart + (size_t)b * 256 * 512 + c;
  float s = 0.f;
#pragma unroll 8
  for (int ns = 0; ns < 256; ++ns) s += p[(size_t)ns * 512];
  tail[i] = 1.0f / ((float)N_ + s);
}

// ---------------------------------------------------------------------------
// K3: GEMM1 split-K, SYMMETRIC: only 10 upper-tri 128x128 tile-pairs.
__global__ __launch_bounds__(256) void k_gemm1(const short* __restrict__ W,
                                               float* __restrict__ matP) {
  __shared__ __align__(16) short As[8192];
  __shared__ __align__(16) short Bs[8192];
  const int TI[NTILES1] = {0, 0, 0, 0, 1, 1, 1, 2, 2, 3};
  const int TJ[NTILES1] = {0, 1, 2, 3, 1, 2, 3, 2, 3, 3};
  int bid = blockIdx.x;
  int ks = bid & 15; bid >>= 4;
  int tt = bid % NTILES1;
  int b = bid / NTILES1;
  int mt = TI[tt], nt = TJ[tt];

  int t = threadIdx.x, lane = t & 63, w = t >> 6;
  int wr = w >> 1, wc = w & 1;
  int prow0 = lane >> 3;
  int swz = ((lane & 7) * 16) ^ (prow0 << 4);

  const short* Wb = W + (size_t)b * C_ * N_;
  const char* gA[4]; const char* gB[4];
  short* lA[4]; short* lB[4];
#pragma unroll
  for (int cc = 0; cc < 4; ++cc) {
    int q = w * 4 + cc;
    int row = q * 8 + prow0;
    gA[cc] = (const char*)(Wb + (size_t)(mt * 128 + row) * N_) + swz;
    gB[cc] = (const char*)(Wb + (size_t)(nt * 128 + row) * N_) + swz;
    lA[cc] = &As[q * 512];
    lB[cc] = &Bs[q * 512];
  }

  f32x4 acc[4][4];
#pragma unroll
  for (int i = 0; i < 4; ++i)
#pragma unroll
    for (int j = 0; j < 4; ++j) acc[i][j] = f32x4{0.f, 0.f, 0.f, 0.f};

  int kbeg = ks * (N_ / KSPLIT1);
  for (int kk = 0; kk < N_ / KSPLIT1; kk += 64) {
    __syncthreads();
    size_t koff = (size_t)(kbeg + kk) * 2;
#pragma unroll
    for (int cc = 0; cc < 4; ++cc) GLOAD16(gA[cc] + koff, lA[cc]);
#pragma unroll
    for (int cc = 0; cc < 4; ++cc) GLOAD16(gB[cc] + koff, lB[cc]);
    __syncthreads();
#pragma unroll
    for (int h = 0; h < 2; ++h) {
      int kb = h * 64 + (lane >> 4) * 16;
      s16x8 af[4], bf[4];
#pragma unroll
      for (int mi = 0; mi < 4; ++mi) {
        int row = wr * 64 + mi * 16 + (lane & 15);
        af[mi] = *(const s16x8*)((const char*)As + row * 128 + (kb ^ ((row & 7) << 4)));
      }
#pragma unroll
      for (int ni = 0; ni < 4; ++ni) {
        int row = wc * 64 + ni * 16 + (lane & 15);
        bf[ni] = *(const s16x8*)((const char*)Bs + row * 128 + (kb ^ ((row & 7) << 4)));
      }
#pragma unroll
      for (int mi = 0; mi < 4; ++mi)
#pragma unroll
        for (int ni = 0; ni < 4; ++ni) mfma16(acc[mi][ni], af[mi], bf[ni]);
    }
  }
  asm volatile("s_nop 7\n\ts_nop 7\n\ts_nop 7" ::);
  float* mp = matP + (((size_t)ks * B_ + b) * NTILES1 + tt) * 16384;
#pragma unroll
  for (int mi = 0; mi < 4; ++mi)
#pragma unroll
    for (int ni = 0; ni < 4; ++ni) {
      int col = wc * 64 + ni * 16 + (lane & 15);
#pragma unroll
      for (int r = 0; r < 4; ++r) {
        int row = wr * 64 + mi * 16 + (lane >> 4) * 4 + r;
        mp[(size_t)row * 128 + col] = acc[mi][ni][r];
      }
    }
}

// K3b: sum split-K partials, convert to bf16, mirror into full matF
__global__ __launch_bounds__(256) void k_redsum2(const float* __restrict__ matP,
                                                 short* __restrict__ matF) {
  const int TI[NTILES1] = {0, 0, 0, 0, 1, 1, 1, 2, 2, 3};
  const int TJ[NTILES1] = {0, 1, 2, 3, 1, 2, 3, 2, 3, 3};
  size_t idx = (size_t)blockIdx.x * 256 + threadIdx.x;
  int b = (int)(idx / (NTILES1 * 16384));
  int rem = (int)(idx % (NTILES1 * 16384));
  int tt = rem >> 14;
  int e = rem & 16383;
  int rowl = e >> 7, col = e & 127;
  float s = 0.f;
#pragma unroll
  for (int ks = 0; ks < KSPLIT1; ++ks)
    s += matP[(((size_t)ks * B_ + b) * NTILES1 + tt) * 16384 + e];
  short v = f2bf(s);
  int ti = TI[tt], tj = TJ[tt];
  short* mb = matF + (size_t)b * C_ * C_;
  mb[(size_t)(ti * 128 + rowl) * C_ + tj * 128 + col] = v;
  if (ti != tj) mb[(size_t)(tj * 128 + col) * C_ + ti * 128 + rowl] = v;
}

// ---------------------------------------------------------------------------
// K4: GEMM2 + epilogue, x-read-free (residual from staged Qn tile; round-8
// proven). 512 thr / 8 waves, 128x128 tile, BK=64 dbuf, counted vmcnt(4).
__global__ __launch_bounds__(512, 4) void k_gemm2(const short* __restrict__ matF,
                                                  const short* __restrict__ QnT,
                                                  const float* __restrict__ csum,
                                                  const float* __restrict__ normv,
                                                  const float* __restrict__ tail,
                                                  const float* __restrict__ gamma,
                                                  float* __restrict__ out) {
  __shared__ __align__(16) short As[2][8192];
  __shared__ __align__(16) short Bs[2][8192];
  int bid = blockIdx.x;
  int nt = bid & 127; bid >>= 7;
  int mt = bid & 3; bid >>= 2;
  int b = bid;

  int t = threadIdx.x, lane = t & 63, w = t >> 6;  // 8 waves
  int wr = w >> 2, wc = w & 3;                     // 2(m) x 4(n) wave grid
  int prow0 = lane >> 3;
  int swz = ((lane & 7) * 16) ^ (prow0 << 4);

  const char* gA[2]; const char* gB[2];
  int lofs[2];
#pragma unroll
  for (int cc = 0; cc < 2; ++cc) {
    int q = w * 2 + cc;
    int row = q * 8 + prow0;
    gA[cc] = (const char*)(matF + ((size_t)b * C_ + mt * 128 + row) * C_) + swz;
    gB[cc] = (const char*)(QnT + ((size_t)b * N_ + nt * 128 + row) * C_) + swz;
    lofs[cc] = q * 512;
  }

  f32x4 acc[4][2];
  float xres[4][2][4];   // captured residual q-values (bf16 widened)
#pragma unroll
  for (int i = 0; i < 4; ++i)
#pragma unroll
    for (int j = 0; j < 2; ++j) {
      acc[i][j] = f32x4{0.f, 0.f, 0.f, 0.f};
#pragma unroll
      for (int r = 0; r < 4; ++r) xres[i][j][r] = 0.f;
    }

#define STG2(pb, kof)                                                          \
  do {                                                                         \
    _Pragma("unroll")                                                          \
    for (int cc = 0; cc < 2; ++cc) GLOAD16(gA[cc] + (kof), &As[pb][lofs[cc]]); \
    _Pragma("unroll")                                                          \
    for (int cc = 0; cc < 2; ++cc) GLOAD16(gB[cc] + (kof), &Bs[pb][lofs[cc]]); \
  } while (0)

  STG2(0, 0);
  int ctk = mt * 2 + wr;   // iteration whose Bs tile holds this wave's residuals
#pragma unroll
  for (int tk = 0; tk < 8; ++tk) {
    if (tk < 7) {
      STG2((tk + 1) & 1, (size_t)(tk + 1) * 128);
      asm volatile("s_waitcnt vmcnt(4)" ::: "memory");
    } else {
      asm volatile("s_waitcnt vmcnt(0)" ::: "memory");
    }
    asm volatile("s_barrier" ::: "memory");
    const char* pA = (const char*)As[tk & 1];
    const char* pB = (const char*)Bs[tk & 1];
#pragma unroll
    for (int h = 0; h < 2; ++h) {
      int kb = h * 64 + (lane >> 4) * 16;
      s16x8 af[4], bf[2];
#pragma unroll
      for (int mi = 0; mi < 4; ++mi) {
        int row = wr * 64 + mi * 16 + (lane & 15);
        af[mi] = *(const s16x8*)(pA + row * 128 + (kb ^ ((row & 7) << 4)));
      }
#pragma unroll
      for (int ni = 0; ni < 2; ++ni) {
        int row = wc * 32 + ni * 16 + (lane & 15);
        bf[ni] = *(const s16x8*)(pB + row * 128 + (kb ^ ((row & 7) << 4)));
      }
#pragma unroll
      for (int mi = 0; mi < 4; ++mi)
#pragma unroll
        for (int ni = 0; ni < 2; ++ni) mfma16(acc[mi][ni], af[mi], bf[ni]);
    }
    // residual capture: Bs row = output col (n), k = output row's local c
    if (tk == ctk) {
#pragma unroll
      for (int mi = 0; mi < 4; ++mi)
#pragma unroll
        for (int r = 0; r < 4; ++r) {
          int kbyte = (mi * 16 + (lane >> 4) * 4 + r) * 2;
#pragma unroll
          for (int ni = 0; ni < 2; ++ni) {
            int row = wc * 32 + ni * 16 + (lane & 15);
            short q = *(const short*)(pB + row * 128 + (kbyte ^ ((row & 7) << 4)));
            xres[mi][ni][r] = bf2f(q);
          }
        }
      asm volatile("s_waitcnt lgkmcnt(0)" ::: "memory");  // latch before overwrite
    }
    asm volatile("s_barrier" ::: "memory");
  }
#undef STG2
  asm volatile("s_nop 7\n\ts_nop 7\n\ts_nop 7" ::);
  float g = gamma[0];
#pragma unroll
  for (int mi = 0; mi < 4; ++mi)
#pragma unroll
    for (int ni = 0; ni < 2; ++ni) {
      int coln = nt * 128 + wc * 32 + ni * 16 + (lane & 15);
      float vs = csum[(size_t)b * N_ + coln];
      float nr = normv[(size_t)b * N_ + coln];
#pragma unroll
      for (int r = 0; r < 4; ++r) {
        int rowg = mt * 128 + wr * 64 + mi * 16 + (lane >> 4) * 4 + r;
        float ts = tail[b * C_ + rowg];
        size_t off = ((size_t)b * C_ + rowg) * N_ + coln;
        out[off] = xres[mi][ni][r] * nr + g * ((vs + acc[mi][ni][r]) * ts);
      }
    }
}

// ===========================================================================
// Tier B fallback (round-1 proven path, used only if ws is small)
// ===========================================================================
__global__ __launch_bounds__(256) void k_stats(const float* __restrict__ x,
                                               float* __restrict__ inv,
                                               float* __restrict__ csum) {
  __shared__ f32x4 ssm[4][64];
  __shared__ f32x4 csm[4][64];
  int t = threadIdx.x, nq = t & 63, cs = t >> 6;
  int g0 = blockIdx.x * 256 + nq * 4;
  int b = g0 >> 14;
  int n = g0 & (N_ - 1);
  const float* p = x + ((size_t)b * C_ + cs * 128) * N_ + n;
  f32x4 ss = {0.f, 0.f, 0.f, 0.f}, sc = {0.f, 0.f, 0.f, 0.f};
  for (int c = 0; c < 128; ++c) {
    f32x4 v = *(const f32x4*)(p + (size_t)c * N_);
    ss += v * v;
    sc += v;
  }
  ssm[cs][nq] = ss; csm[cs][nq] = sc;
  __syncthreads();
  if (t < 64) {
    f32x4 s1 = ssm[0][t] + ssm[1][t] + ssm[2][t] + ssm[3][t];
    f32x4 c1 = csm[0][t] + csm[1][t] + csm[2][t] + csm[3][t];
    f32x4 r;
#pragma unroll
    for (int j = 0; j < 4; ++j) r[j] = 1.0f / sqrtf(s1[j]);
    int g = blockIdx.x * 256 + t * 4;
    *(f32x4*)(inv + g) = r;
    *(f32x4*)(csum + g) = c1;
  }
}

__global__ __launch_bounds__(256) void k_tailor_fb(const float* __restrict__ x,
                                                   const float* __restrict__ inv,
                                                   const float* __restrict__ csum,
                                                   float* __restrict__ tail) {
  int b = blockIdx.x >> 9;
  const float* row = x + (size_t)blockIdx.x * N_;
  const float* ib = inv + b * N_;
  const float* cb = csum + b * N_;
  int t = threadIdx.x;
  float acc = 0.f;
  for (int i = t * 4; i < N_; i += 1024) {
    f32x4 v = *(const f32x4*)(row + i);
    f32x4 iv = *(const f32x4*)(ib + i);
    f32x4 cv = *(const f32x4*)(cb + i);
#pragma unroll
    for (int j = 0; j < 4; ++j) acc += v[j] * (iv[j] * fmaf(iv[j], cv[j], EPSF));
  }
#pragma unroll
  for (int off = 32; off > 0; off >>= 1) acc += __shfl_down(acc, off, 64);
  __shared__ float red[4];
  if ((t & 63) == 0) red[t >> 6] = acc;
  __syncthreads();
  if (t == 0) tail[blockIdx.x] = 1.0f / ((float)N_ + red[0] + red[1] + red[2] + red[3]);
}

__global__ __launch_bounds__(256) void k_gemm1_fb(const float* __restrict__ x,
                                                  const float* __restrict__ inv,
                                                  float* __restrict__ mpart,
                                                  int ksplit) {
  __shared__ short As[128 * 40];
  __shared__ short Bs[128 * 40];
  int bid = blockIdx.x;
  int ks = bid % ksplit; bid /= ksplit;
  int nt = bid & 3; bid >>= 2;
  int mt = bid & 3; bid >>= 2;
  int b = bid;
  int kch = N_ / ksplit;
  int kbeg = ks * kch, kend = kbeg + kch;
  int t = threadIdx.x, lane = t & 63, w = t >> 6, wr = w >> 1, wc = w & 1;
  int srow = t >> 1, skh = t & 1;
  const float* xb = x + (size_t)b * C_ * N_;
  const float* ga = xb + (size_t)(mt * 128 + srow) * N_ + skh * 16;
  const float* gb = xb + (size_t)(nt * 128 + srow) * N_ + skh * 16;
  const float* gi = inv + b * N_ + skh * 16;
  f32x4 acc[4][4];
#pragma unroll
  for (int i = 0; i < 4; ++i)
#pragma unroll
    for (int j = 0; j < 4; ++j) acc[i][j] = f32x4{0.f, 0.f, 0.f, 0.f};
  int ldsw = srow * 40 + skh * 16;
  int lra = (wr * 64 + (lane & 15)) * 40 + (lane >> 4) * 8;
  int lrb = (wc * 64 + (lane & 15)) * 40 + (lane >> 4) * 8;
  for (int kk = kbeg; kk < kend; kk += 32) {
    __syncthreads();
    {
      f32x4 a0 = *(const f32x4*)(ga + kk), a1 = *(const f32x4*)(ga + kk + 4);
      f32x4 a2 = *(const f32x4*)(ga + kk + 8), a3 = *(const f32x4*)(ga + kk + 12);
      f32x4 b0 = *(const f32x4*)(gb + kk), b1 = *(const f32x4*)(gb + kk + 4);
      f32x4 b2 = *(const f32x4*)(gb + kk + 8), b3 = *(const f32x4*)(gb + kk + 12);
      f32x4 i0 = *(const f32x4*)(gi + kk), i1 = *(const f32x4*)(gi + kk + 4);
      f32x4 i2 = *(const f32x4*)(gi + kk + 8), i3 = *(const f32x4*)(gi + kk + 12);
      *(s16x8*)&As[ldsw] = pack8(a0, a1);
      *(s16x8*)&As[ldsw + 8] = pack8(a2, a3);
      *(s16x8*)&Bs[ldsw] = pack8(b0 * i0, b1 * i1);
      *(s16x8*)&Bs[ldsw + 8] = pack8(b2 * i2, b3 * i3);
    }
    __syncthreads();
    s16x8 af[4], bf[4];
#pragma unroll
    for (int mi = 0; mi < 4; ++mi) af[mi] = *(const s16x8*)&As[lra + mi * 16 * 40];
#pragma unroll
    for (int ni = 0; ni < 4; ++ni) bf[ni] = *(const s16x8*)&Bs[lrb + ni * 16 * 40];
#pragma unroll
    for (int mi = 0; mi < 4; ++mi)
#pragma unroll
      for (int ni = 0; ni < 4; ++ni) mfma16(acc[mi][ni], af[mi], bf[ni]);
  }
  asm volatile("s_nop 7\n\ts_nop 7\n\ts_nop 7" ::);
  float* mp = mpart + ((size_t)ks * B_ + b) * C_ * C_;
#pragma unroll
  for (int mi = 0; mi < 4; ++mi)
#pragma unroll
    for (int ni = 0; ni < 4; ++ni) {
      int col = nt * 128 + wc * 64 + ni * 16 + (lane & 15);
#pragma unroll
      for (int r = 0; r < 4; ++r) {
        int rowg = mt * 128 + wr * 64 + mi * 16 + (lane >> 4) * 4 + r;
        mp[(size_t)rowg * C_ + col] = acc[mi][ni][r];
      }
    }
}

__global__ __launch_bounds__(256) void k_reduce_fb(const float* __restrict__ mpart,
                                                   float* __restrict__ mfull,
                                                   int ksplit) {
  size_t i = (size_t)blockIdx.x * 256 + threadIdx.x;
  float s = 0.f;
  for (int k = 0; k < ksplit; ++k) s += mpart[(size_t)k * (B_ * C_ * C_) + i];
  mfull[i] = s;
}

__global__ __launch_bounds__(256) void k_gemm2_fb(const float* __restrict__ x,
                                                  const float* __restrict__ mat,
                                                  const float* __restrict__ inv,
                                                  const float* __restrict__ csum,
                                                  const float* __restrict__ tail,
                                                  const float* __restrict__ gamma,
                                                  float* __restrict__ out) {
  __shared__ short As[128 * 40];
  __shared__ short Bs[128 * 40];
  int bid = blockIdx.x;
  int nt = bid & 127; bid >>= 7;
  int mt = bid & 3; bid >>= 2;
  int b = bid;
  int t = threadIdx.x, lane = t & 63, w = t >> 6, wr = w >> 1, wc = w & 1;
  int srow = t >> 1, skh = t & 1;
  const float* gA = mat + ((size_t)b * C_ + mt * 128 + srow) * C_ + skh * 16;
  int kb = t >> 5, cbl = t & 31;
  int k0l = kb * 4, n0 = cbl * 4;
  const float* xb = x + (size_t)b * C_ * N_;
  const float* gB = xb + (size_t)k0l * N_ + nt * 128 + n0;
  f32x4 ivn = *(const f32x4*)(inv + b * N_ + nt * 128 + n0);
  f32x4 acc[4][4];
#pragma unroll
  for (int i = 0; i < 4; ++i)
#pragma unroll
    for (int j = 0; j < 4; ++j) acc[i][j] = f32x4{0.f, 0.f, 0.f, 0.f};
  int ldsw = srow * 40 + skh * 16;
  int lra = (wr * 64 + (lane & 15)) * 40 + (lane >> 4) * 8;
  int lrb = (wc * 64 + (lane & 15)) * 40 + (lane >> 4) * 8;
  for (int kk = 0; kk < C_; kk += 32) {
    __syncthreads();
    {
      f32x4 a0 = *(const f32x4*)(gA + kk), a1 = *(const f32x4*)(gA + kk + 4);
      f32x4 a2 = *(const f32x4*)(gA + kk + 8), a3 = *(const f32x4*)(gA + kk + 12);
      *(s16x8*)&As[ldsw] = pack8(a0, a1);
      *(s16x8*)&As[ldsw + 8] = pack8(a2, a3);
      const float* pB = gB + (size_t)kk * N_;
      f32x4 v0 = *(const f32x4*)(pB);
      f32x4 v1 = *(const f32x4*)(pB + N_);
      f32x4 v2 = *(const f32x4*)(pB + 2 * N_);
      f32x4 v3 = *(const f32x4*)(pB + 3 * N_);
#pragma unroll
      for (int cc = 0; cc < 4; ++cc) {
        s16x4 q;
        q[0] = f2bf(v0[cc] * ivn[cc]);
        q[1] = f2bf(v1[cc] * ivn[cc]);
        q[2] = f2bf(v2[cc] * ivn[cc]);
        q[3] = f2bf(v3[cc] * ivn[cc]);
        *(s16x4*)&Bs[(n0 + cc) * 40 + k0l] = q;
      }
    }
    __syncthreads();
    s16x8 af[4], bf[4];
#pragma unroll
    for (int mi = 0; mi < 4; ++mi) af[mi] = *(const s16x8*)&As[lra + mi * 16 * 40];
#pragma unroll
    for (int ni = 0; ni < 4; ++ni) bf[ni] = *(const s16x8*)&Bs[lrb + ni * 16 * 40];
#pragma unroll
    for (int mi = 0; mi < 4; ++mi)
#pragma unroll
      for (int ni = 0; ni < 4; ++ni) mfma16(acc[mi][ni], af[mi], bf[ni]);
  }
  asm volatile("s_nop 7\n\ts_nop 7\n\ts_nop 7" ::);
  float g = gamma[0];
#pragma unroll
  for (int mi = 0; mi < 4; ++mi)
#pragma unroll
    for (int ni = 0; ni < 4; ++ni) {
      int coln = nt * 128 + wc * 64 + ni * 16 + (lane & 15);
      float vs = csum[b * N_ + coln];
#pragma unroll
      for (int r = 0; r < 4; ++r) {
        int rowg = mt * 128 + wr * 64 + mi * 16 + (lane >> 4) * 4 + r;
        float ts = tail[b * C_ + rowg];
        size_t off = ((size_t)b * C_ + rowg) * N_ + coln;
        out[off] = x[off] + g * ((vs + acc[mi][ni][r]) * ts);
      }
    }
}

// ---------------------------------------------------------------------------
extern "C" void kernel_launch(void* const* d_in, const int* in_sizes, int n_in,
                              void* d_out, int out_size, void* d_ws, size_t ws_size,
                              hipStream_t stream) {
  const float* x = (const float*)d_in[0];
  const float* gamma = (const float*)d_in[1];
  float* out = (float*)d_out;
  float* wsf = (float*)d_ws;

  // Tier A ws layout (floats): csum[131072] norm[131072] tail[4096]
  //   matF[1048576 slots = 2M bf16] QnT[33554432 slots = 64M bf16]
  const size_t needA = 139476992ull;
  if (ws_size >= needA) {
    float* csum = wsf;
    float* normv = wsf + 131072;
    float* tail = wsf + 262144;
    short* matF = (short*)(wsf + 266240);
    short* QnT = (short*)(wsf + 1314816);
    // d_out scratch: W bf16 [0,128MB) | matP fp32 [128MB,208MB) | tpart [208MB,212MB)
    short* W = (short*)d_out;
    float* matP = (float*)d_out + 33554432ull;
    float* tpart = (float*)d_out + 54525952ull;

    k_prep5<<<2048, 512, 0, stream>>>(x, csum, normv, W, QnT, tpart);
    k_tailor2<<<16, 256, 0, stream>>>(tpart, tail);
    k_gemm1<<<B_ * NTILES1 * KSPLIT1, 256, 0, stream>>>(W, matP);
    k_redsum2<<<(B_ * NTILES1 * 16384) / 256, 256, 0, stream>>>(matP, matF);
    k_gemm2<<<4096, 512, 0, stream>>>(matF, QnT, csum, normv, tail, gamma, out);
  } else {
    // Tier B: round-1 proven path
    float* inv = wsf;
    float* csum = wsf + 131072;
    float* tail = wsf + 262144;
    float* matP = wsf + 266240;
    int ksplit = (ws_size >= 43008000ull) ? 4 : 1;
    float* matF = (ksplit > 1) ? (matP + (size_t)ksplit * 2097152) : matP;

    k_stats<<<512, 256, 0, stream>>>(x, inv, csum);
    k_tailor_fb<<<B_ * C_, 256, 0, stream>>>(x, inv, csum, tail);
    k_gemm1_fb<<<B_ * 16 * ksplit, 256, 0, stream>>>(x, inv, matP, ksplit);
    if (ksplit > 1) k_reduce_fb<<<8192, 256, 0, stream>>>(matP, matF, ksplit);
    k_gemm2_fb<<<B_ * 4 * 128, 256, 0, stream>>>(x, matF, inv, csum, tail, gamma, out);
  }
}

// Round 12
// 330.121 us; speedup vs baseline: 1.1882x; 1.0022x over previous
//
#include <hip/hip_runtime.h>
#include <hip/hip_bf16.h>

#define B_ 8
#define C_ 512
#define N_ 16384
#define EPSF 1e-6f
#define KSPLIT1 8
#define NTILES1 10

typedef float f32x4 __attribute__((ext_vector_type(4)));
typedef short s16x8 __attribute__((ext_vector_type(8)));
typedef short s16x4 __attribute__((ext_vector_type(4)));

__device__ __forceinline__ short f2bf(float f) {
  union { float f; unsigned u; } v; v.f = f;
  unsigned r = v.u + 0x7fffu + ((v.u >> 16) & 1u);  // RNE
  return (short)(r >> 16);
}

__device__ __forceinline__ float bf2f(short s) {
  union { float f; unsigned u; } v;
  v.u = ((unsigned)(unsigned short)s) << 16;
  return v.f;
}

__device__ __forceinline__ s16x8 pack8(f32x4 a, f32x4 b) {
  s16x8 r;
  r[0] = f2bf(a[0]); r[1] = f2bf(a[1]); r[2] = f2bf(a[2]); r[3] = f2bf(a[3]);
  r[4] = f2bf(b[0]); r[5] = f2bf(b[1]); r[6] = f2bf(b[2]); r[7] = f2bf(b[3]);
  return r;
}

__device__ __forceinline__ void mfma16(f32x4& d, s16x8 a, s16x8 b) {
  asm("v_mfma_f32_16x16x32_bf16 %0, %1, %2, %0" : "+v"(d) : "v"(a), "v"(b));
}

// async global->LDS, 16B per lane, LDS dest = wave-uniform base + lane*16
#define GLOAD16(gp, lp)                                                        \
  __builtin_amdgcn_global_load_lds(                                            \
      (const __attribute__((address_space(1))) unsigned int*)(gp),             \
      (__attribute__((address_space(3))) unsigned int*)(lp), 16, 0, 0)

// ---------------------------------------------------------------------------
// K1 (fused): per block = (b, 64-n slab, all 512 c). One HBM x-pass.
// prep2's proven memory patterns, 512 threads (2 blk/CU -> 16 waves/CU).
__global__ __launch_bounds__(512) void k_prep5(const float* __restrict__ x,
                                               float* __restrict__ csum,
                                               float* __restrict__ normv,
                                               short* __restrict__ W,
                                               short* __restrict__ QnT,
                                               float* __restrict__ tpart) {
  __shared__ short xbf[512 * 64];   // [c][n] bf16, 64KB
  __shared__ f32x4 pss[8][16], pcs[8][16];
  __shared__ float invs[64], rss[64], t2s[64];
  int blk = blockIdx.x;
  int nslab = blk & 255, b = blk >> 8;
  int n0g = nslab * 64;
  int t = threadIdx.x;

  // ---- phase 1: thread = (nq, cs) = 16 n-quads x 32 c-segs of 16 rows
  {
    int nq = t & 15, cs = t >> 4;
    const float* xp = x + ((size_t)b * C_ + cs * 16) * N_ + n0g + nq * 4;
    short* lp = &xbf[(cs * 16) * 64 + nq * 4];
    f32x4 ss = {0.f, 0.f, 0.f, 0.f}, sc = {0.f, 0.f, 0.f, 0.f};
#pragma unroll
    for (int r = 0; r < 16; ++r) {
      f32x4 v = *(const f32x4*)(xp + (size_t)r * N_);
      ss += v * v;
      sc += v;
      s16x4 bv;
      bv[0] = f2bf(v[0]); bv[1] = f2bf(v[1]); bv[2] = f2bf(v[2]); bv[3] = f2bf(v[3]);
      *(s16x4*)(lp + r * 64) = bv;
    }
    // reduce the 4 cs-segs within each wave (cs low bits = lane bits 4..5)
#pragma unroll
    for (int j = 0; j < 4; ++j) {
      float a = ss[j], c = sc[j];
      a += __shfl_xor(a, 16, 64); c += __shfl_xor(c, 16, 64);
      a += __shfl_xor(a, 32, 64); c += __shfl_xor(c, 32, 64);
      ss[j] = a; sc[j] = c;
    }
    int w = t >> 6;
    if ((t & 63) < 16) { pss[w][nq] = ss; pcs[w][nq] = sc; }
  }
  __syncthreads();
  if (t < 64) {
    int q = t >> 2, j = t & 3;
    float s = 0.f, c = 0.f;
#pragma unroll
    for (int k = 0; k < 8; ++k) { s += pss[k][q][j]; c += pcs[k][q][j]; }
    float nr = sqrtf(s);
    float iv = 1.0f / nr;
    invs[t] = iv;
    rss[t] = sqrtf(iv);
    t2s[t] = fmaf(c, iv, EPSF);
    csum[(size_t)b * N_ + n0g + t] = c;
    normv[(size_t)b * N_ + n0g + t] = nr;
  }
  __syncthreads();

  // ---- phase 2: thread = (ng, cg) = 8 n-octs x 64 c-chunks of 8
  int ng = t & 7, cg = t >> 3;
  int nl = ng * 8;
  float ivl[8], rsl[8], t2l[8];
#pragma unroll
  for (int j = 0; j < 8; ++j) {
    ivl[j] = invs[nl + j];
    rsl[j] = rss[nl + j];
    t2l[j] = t2s[nl + j];
  }
  int c0 = cg * 8;
  s16x8 qcol[8];
  float tpc[8];
#pragma unroll
  for (int i = 0; i < 8; ++i) {
    s16x8 xv = *(const s16x8*)&xbf[(c0 + i) * 64 + nl];
    s16x8 wv;
    float tp = 0.f;
#pragma unroll
    for (int j = 0; j < 8; ++j) {
      float xf = bf2f(xv[j]);
      wv[j] = f2bf(xf * rsl[j]);
      float q = xf * ivl[j];
      qcol[j][i] = f2bf(q);
      tp = fmaf(q, t2l[j], tp);
    }
    *(s16x8*)(W + ((size_t)b * C_ + c0 + i) * N_ + n0g + nl) = wv;
    tpc[i] = tp;
  }
#pragma unroll
  for (int j = 0; j < 8; ++j)
    *(s16x8*)(QnT + ((size_t)b * N_ + n0g + nl + j) * C_ + c0) = qcol[j];
#pragma unroll
  for (int i = 0; i < 8; ++i) {
    float v2 = tpc[i];
    v2 += __shfl_xor(v2, 1, 64);
    v2 += __shfl_xor(v2, 2, 64);
    v2 += __shfl_xor(v2, 4, 64);
    if (ng == 0) tpart[((size_t)b * 256 + nslab) * 512 + c0 + i] = v2;
  }
}

// K1b: finalize tailor over 256 nslab partials (layout [b][nslab][c])
__global__ __launch_bounds__(256) void k_tailor2(const float* __restrict__ tpart,
                                                 float* __restrict__ tail) {
  int i = blockIdx.x * 256 + threadIdx.x;  // 0..4095 = (b,c)
  int b = i >> 9, c = i & 511;
  const float* p = tpart + (size_t)b * 256 * 512 + c;
  float s = 0.f;
#pragma unroll 8
  for (int ns = 0; ns < 256; ++ns) s += p[(size_t)ns * 512];
  tail[i] = 1.0f / ((float)N_ + s);
}

// ---------------------------------------------------------------------------
// K3: GEMM1 split-K (KSPLIT1=8), SYMMETRIC: 10 upper-tri 128x128 tile-pairs.
__global__ __launch_bounds__(256) void k_gemm1(const short* __restrict__ W,
                                               float* __restrict__ matP) {
  __shared__ __align__(16) short As[8192];
  __shared__ __align__(16) short Bs[8192];
  const int TI[NTILES1] = {0, 0, 0, 0, 1, 1, 1, 2, 2, 3};
  const int TJ[NTILES1] = {0, 1, 2, 3, 1, 2, 3, 2, 3, 3};
  int bid = blockIdx.x;
  int ks = bid & 7; bid >>= 3;
  int tt = bid % NTILES1;
  int b = bid / NTILES1;
  int mt = TI[tt], nt = TJ[tt];

  int t = threadIdx.x, lane = t & 63, w = t >> 6;
  int wr = w >> 1, wc = w & 1;
  int prow0 = lane >> 3;
  int swz = ((lane & 7) * 16) ^ (prow0 << 4);

  const short* Wb = W + (size_t)b * C_ * N_;
  const char* gA[4]; const char* gB[4];
  short* lA[4]; short* lB[4];
#pragma unroll
  for (int cc = 0; cc < 4; ++cc) {
    int q = w * 4 + cc;
    int row = q * 8 + prow0;
    gA[cc] = (const char*)(Wb + (size_t)(mt * 128 + row) * N_) + swz;
    gB[cc] = (const char*)(Wb + (size_t)(nt * 128 + row) * N_) + swz;
    lA[cc] = &As[q * 512];
    lB[cc] = &Bs[q * 512];
  }

  f32x4 acc[4][4];
#pragma unroll
  for (int i = 0; i < 4; ++i)
#pragma unroll
    for (int j = 0; j < 4; ++j) acc[i][j] = f32x4{0.f, 0.f, 0.f, 0.f};

  int kbeg = ks * (N_ / KSPLIT1);
  for (int kk = 0; kk < N_ / KSPLIT1; kk += 64) {
    __syncthreads();
    size_t koff = (size_t)(kbeg + kk) * 2;
#pragma unroll
    for (int cc = 0; cc < 4; ++cc) GLOAD16(gA[cc] + koff, lA[cc]);
#pragma unroll
    for (int cc = 0; cc < 4; ++cc) GLOAD16(gB[cc] + koff, lB[cc]);
    __syncthreads();
#pragma unroll
    for (int h = 0; h < 2; ++h) {
      int kb = h * 64 + (lane >> 4) * 16;
      s16x8 af[4], bf[4];
#pragma unroll
      for (int mi = 0; mi < 4; ++mi) {
        int row = wr * 64 + mi * 16 + (lane & 15);
        af[mi] = *(const s16x8*)((const char*)As + row * 128 + (kb ^ ((row & 7) << 4)));
      }
#pragma unroll
      for (int ni = 0; ni < 4; ++ni) {
        int row = wc * 64 + ni * 16 + (lane & 15);
        bf[ni] = *(const s16x8*)((const char*)Bs + row * 128 + (kb ^ ((row & 7) << 4)));
      }
#pragma unroll
      for (int mi = 0; mi < 4; ++mi)
#pragma unroll
        for (int ni = 0; ni < 4; ++ni) mfma16(acc[mi][ni], af[mi], bf[ni]);
    }
  }
  asm volatile("s_nop 7\n\ts_nop 7\n\ts_nop 7" ::);
  float* mp = matP + (((size_t)ks * B_ + b) * NTILES1 + tt) * 16384;
#pragma unroll
  for (int mi = 0; mi < 4; ++mi)
#pragma unroll
    for (int ni = 0; ni < 4; ++ni) {
      int col = wc * 64 + ni * 16 + (lane & 15);
#pragma unroll
      for (int r = 0; r < 4; ++r) {
        int row = wr * 64 + mi * 16 + (lane >> 4) * 4 + r;
        mp[(size_t)row * 128 + col] = acc[mi][ni][r];
      }
    }
}

// K3b: sum split-K partials, convert to bf16, mirror into full matF
__global__ __launch_bounds__(256) void k_redsum2(const float* __restrict__ matP,
                                                 short* __restrict__ matF) {
  const int TI[NTILES1] = {0, 0, 0, 0, 1, 1, 1, 2, 2, 3};
  const int TJ[NTILES1] = {0, 1, 2, 3, 1, 2, 3, 2, 3, 3};
  size_t idx = (size_t)blockIdx.x * 256 + threadIdx.x;
  int b = (int)(idx / (NTILES1 * 16384));
  int rem = (int)(idx % (NTILES1 * 16384));
  int tt = rem >> 14;
  int e = rem & 16383;
  int rowl = e >> 7, col = e & 127;
  float s = 0.f;
#pragma unroll
  for (int ks = 0; ks < KSPLIT1; ++ks)
    s += matP[(((size_t)ks * B_ + b) * NTILES1 + tt) * 16384 + e];
  short v = f2bf(s);
  int ti = TI[tt], tj = TJ[tt];
  short* mb = matF + (size_t)b * C_ * C_;
  mb[(size_t)(ti * 128 + rowl) * C_ + tj * 128 + col] = v;
  if (ti != tj) mb[(size_t)(tj * 128 + col) * C_ + ti * 128 + rowl] = v;
}

// ---------------------------------------------------------------------------
// K4: GEMM2 + epilogue, x-read-free (residual from staged Qn tile; round-8
// proven). 512 thr / 8 waves, 128x128 tile, BK=64 dbuf, counted vmcnt(4).
__global__ __launch_bounds__(512, 4) void k_gemm2(const short* __restrict__ matF,
                                                  const short* __restrict__ QnT,
                                                  const float* __restrict__ csum,
                                                  const float* __restrict__ normv,
                                                  const float* __restrict__ tail,
                                                  const float* __restrict__ gamma,
                                                  float* __restrict__ out) {
  __shared__ __align__(16) short As[2][8192];
  __shared__ __align__(16) short Bs[2][8192];
  int bid = blockIdx.x;
  int nt = bid & 127; bid >>= 7;
  int mt = bid & 3; bid >>= 2;
  int b = bid;

  int t = threadIdx.x, lane = t & 63, w = t >> 6;  // 8 waves
  int wr = w >> 2, wc = w & 3;                     // 2(m) x 4(n) wave grid
  int prow0 = lane >> 3;
  int swz = ((lane & 7) * 16) ^ (prow0 << 4);

  const char* gA[2]; const char* gB[2];
  int lofs[2];
#pragma unroll
  for (int cc = 0; cc < 2; ++cc) {
    int q = w * 2 + cc;
    int row = q * 8 + prow0;
    gA[cc] = (const char*)(matF + ((size_t)b * C_ + mt * 128 + row) * C_) + swz;
    gB[cc] = (const char*)(QnT + ((size_t)b * N_ + nt * 128 + row) * C_) + swz;
    lofs[cc] = q * 512;
  }

  f32x4 acc[4][2];
  float xres[4][2][4];   // captured residual q-values (bf16 widened)
#pragma unroll
  for (int i = 0; i < 4; ++i)
#pragma unroll
    for (int j = 0; j < 2; ++j) {
      acc[i][j] = f32x4{0.f, 0.f, 0.f, 0.f};
#pragma unroll
      for (int r = 0; r < 4; ++r) xres[i][j][r] = 0.f;
    }

#define STG2(pb, kof)                                                          \
  do {                                                                         \
    _Pragma("unroll")                                                          \
    for (int cc = 0; cc < 2; ++cc) GLOAD16(gA[cc] + (kof), &As[pb][lofs[cc]]); \
    _Pragma("unroll")                                                          \
    for (int cc = 0; cc < 2; ++cc) GLOAD16(gB[cc] + (kof), &Bs[pb][lofs[cc]]); \
  } while (0)

  STG2(0, 0);
  int ctk = mt * 2 + wr;   // iteration whose Bs tile holds this wave's residuals
#pragma unroll
  for (int tk = 0; tk < 8; ++tk) {
    if (tk < 7) {
      STG2((tk + 1) & 1, (size_t)(tk + 1) * 128);
      asm volatile("s_waitcnt vmcnt(4)" ::: "memory");
    } else {
      asm volatile("s_waitcnt vmcnt(0)" ::: "memory");
    }
    asm volatile("s_barrier" ::: "memory");
    const char* pA = (const char*)As[tk & 1];
    const char* pB = (const char*)Bs[tk & 1];
#pragma unroll
    for (int h = 0; h < 2; ++h) {
      int kb = h * 64 + (lane >> 4) * 16;
      s16x8 af[4], bf[2];
#pragma unroll
      for (int mi = 0; mi < 4; ++mi) {
        int row = wr * 64 + mi * 16 + (lane & 15);
        af[mi] = *(const s16x8*)(pA + row * 128 + (kb ^ ((row & 7) << 4)));
      }
#pragma unroll
      for (int ni = 0; ni < 2; ++ni) {
        int row = wc * 32 + ni * 16 + (lane & 15);
        bf[ni] = *(const s16x8*)(pB + row * 128 + (kb ^ ((row & 7) << 4)));
      }
#pragma unroll
      for (int mi = 0; mi < 4; ++mi)
#pragma unroll
        for (int ni = 0; ni < 2; ++ni) mfma16(acc[mi][ni], af[mi], bf[ni]);
    }
    // residual capture: Bs row = output col (n), k = output row's local c
    if (tk == ctk) {
#pragma unroll
      for (int mi = 0; mi < 4; ++mi)
#pragma unroll
        for (int r = 0; r < 4; ++r) {
          int kbyte = (mi * 16 + (lane >> 4) * 4 + r) * 2;
#pragma unroll
          for (int ni = 0; ni < 2; ++ni) {
            int row = wc * 32 + ni * 16 + (lane & 15);
            short q = *(const short*)(pB + row * 128 + (kbyte ^ ((row & 7) << 4)));
            xres[mi][ni][r] = bf2f(q);
          }
        }
      asm volatile("s_waitcnt lgkmcnt(0)" ::: "memory");  // latch before overwrite
    }
    asm volatile("s_barrier" ::: "memory");
  }
#undef STG2
  asm volatile("s_nop 7\n\ts_nop 7\n\ts_nop 7" ::);
  float g = gamma[0];
#pragma unroll
  for (int mi = 0; mi < 4; ++mi)
#pragma unroll
    for (int ni = 0; ni < 2; ++ni) {
      int coln = nt * 128 + wc * 32 + ni * 16 + (lane & 15);
      float vs = csum[(size_t)b * N_ + coln];
      float nr = normv[(size_t)b * N_ + coln];
#pragma unroll
      for (int r = 0; r < 4; ++r) {
        int rowg = mt * 128 + wr * 64 + mi * 16 + (lane >> 4) * 4 + r;
        float ts = tail[b * C_ + rowg];
        size_t off = ((size_t)b * C_ + rowg) * N_ + coln;
        out[off] = xres[mi][ni][r] * nr + g * ((vs + acc[mi][ni][r]) * ts);
      }
    }
}

// ===========================================================================
// Tier B fallback (round-1 proven path, used only if ws is small)
// ===========================================================================
__global__ __launch_bounds__(256) void k_stats(const float* __restrict__ x,
                                               float* __restrict__ inv,
                                               float* __restrict__ csum) {
  __shared__ f32x4 ssm[4][64];
  __shared__ f32x4 csm[4][64];
  int t = threadIdx.x, nq = t & 63, cs = t >> 6;
  int g0 = blockIdx.x * 256 + nq * 4;
  int b = g0 >> 14;
  int n = g0 & (N_ - 1);
  const float* p = x + ((size_t)b * C_ + cs * 128) * N_ + n;
  f32x4 ss = {0.f, 0.f, 0.f, 0.f}, sc = {0.f, 0.f, 0.f, 0.f};
  for (int c = 0; c < 128; ++c) {
    f32x4 v = *(const f32x4*)(p + (size_t)c * N_);
    ss += v * v;
    sc += v;
  }
  ssm[cs][nq] = ss; csm[cs][nq] = sc;
  __syncthreads();
  if (t < 64) {
    f32x4 s1 = ssm[0][t] + ssm[1][t] + ssm[2][t] + ssm[3][t];
    f32x4 c1 = csm[0][t] + csm[1][t] + csm[2][t] + csm[3][t];
    f32x4 r;
#pragma unroll
    for (int j = 0; j < 4; ++j) r[j] = 1.0f / sqrtf(s1[j]);
    int g = blockIdx.x * 256 + t * 4;
    *(f32x4*)(inv + g) = r;
    *(f32x4*)(csum + g) = c1;
  }
}

__global__ __launch_bounds__(256) void k_tailor_fb(const float* __restrict__ x,
                                                   const float* __restrict__ inv,
                                                   const float* __restrict__ csum,
                                                   float* __restrict__ tail) {
  int b = blockIdx.x >> 9;
  const float* row = x + (size_t)blockIdx.x * N_;
  const float* ib = inv + b * N_;
  const float* cb = csum + b * N_;
  int t = threadIdx.x;
  float acc = 0.f;
  for (int i = t * 4; i < N_; i += 1024) {
    f32x4 v = *(const f32x4*)(row + i);
    f32x4 iv = *(const f32x4*)(ib + i);
    f32x4 cv = *(const f32x4*)(cb + i);
#pragma unroll
    for (int j = 0; j < 4; ++j) acc += v[j] * (iv[j] * fmaf(iv[j], cv[j], EPSF));
  }
#pragma unroll
  for (int off = 32; off > 0; off >>= 1) acc += __shfl_down(acc, off, 64);
  __shared__ float red[4];
  if ((t & 63) == 0) red[t >> 6] = acc;
  __syncthreads();
  if (t == 0) tail[blockIdx.x] = 1.0f / ((float)N_ + red[0] + red[1] + red[2] + red[3]);
}

__global__ __launch_bounds__(256) void k_gemm1_fb(const float* __restrict__ x,
                                                  const float* __restrict__ inv,
                                                  float* __restrict__ mpart,
                                                  int ksplit) {
  __shared__ short As[128 * 40];
  __shared__ short Bs[128 * 40];
  int bid = blockIdx.x;
  int ks = bid % ksplit; bid /= ksplit;
  int nt = bid & 3; bid >>= 2;
  int mt = bid & 3; bid >>= 2;
  int b = bid;
  int kch = N_ / ksplit;
  int kbeg = ks * kch, kend = kbeg + kch;
  int t = threadIdx.x, lane = t & 63, w = t >> 6, wr = w >> 1, wc = w & 1;
  int srow = t >> 1, skh = t & 1;
  const float* xb = x + (size_t)b * C_ * N_;
  const float* ga = xb + (size_t)(mt * 128 + srow) * N_ + skh * 16;
  const float* gb = xb + (size_t)(nt * 128 + srow) * N_ + skh * 16;
  const float* gi = inv + b * N_ + skh * 16;
  f32x4 acc[4][4];
#pragma unroll
  for (int i = 0; i < 4; ++i)
#pragma unroll
    for (int j = 0; j < 4; ++j) acc[i][j] = f32x4{0.f, 0.f, 0.f, 0.f};
  int ldsw = srow * 40 + skh * 16;
  int lra = (wr * 64 + (lane & 15)) * 40 + (lane >> 4) * 8;
  int lrb = (wc * 64 + (lane & 15)) * 40 + (lane >> 4) * 8;
  for (int kk = kbeg; kk < kend; kk += 32) {
    __syncthreads();
    {
      f32x4 a0 = *(const f32x4*)(ga + kk), a1 = *(const f32x4*)(ga + kk + 4);
      f32x4 a2 = *(const f32x4*)(ga + kk + 8), a3 = *(const f32x4*)(ga + kk + 12);
      f32x4 b0 = *(const f32x4*)(gb + kk), b1 = *(const f32x4*)(gb + kk + 4);
      f32x4 b2 = *(const f32x4*)(gb + kk + 8), b3 = *(const f32x4*)(gb + kk + 12);
      f32x4 i0 = *(const f32x4*)(gi + kk), i1 = *(const f32x4*)(gi + kk + 4);
      f32x4 i2 = *(const f32x4*)(gi + kk + 8), i3 = *(const f32x4*)(gi + kk + 12);
      *(s16x8*)&As[ldsw] = pack8(a0, a1);
      *(s16x8*)&As[ldsw + 8] = pack8(a2, a3);
      *(s16x8*)&Bs[ldsw] = pack8(b0 * i0, b1 * i1);
      *(s16x8*)&Bs[ldsw + 8] = pack8(b2 * i2, b3 * i3);
    }
    __syncthreads();
    s16x8 af[4], bf[4];
#pragma unroll
    for (int mi = 0; mi < 4; ++mi) af[mi] = *(const s16x8*)&As[lra + mi * 16 * 40];
#pragma unroll
    for (int ni = 0; ni < 4; ++ni) bf[ni] = *(const s16x8*)&Bs[lrb + ni * 16 * 40];
#pragma unroll
    for (int mi = 0; mi < 4; ++mi)
#pragma unroll
      for (int ni = 0; ni < 4; ++ni) mfma16(acc[mi][ni], af[mi], bf[ni]);
  }
  asm volatile("s_nop 7\n\ts_nop 7\n\ts_nop 7" ::);
  float* mp = mpart + ((size_t)ks * B_ + b) * C_ * C_;
#pragma unroll
  for (int mi = 0; mi < 4; ++mi)
#pragma unroll
    for (int ni = 0; ni < 4; ++ni) {
      int col = nt * 128 + wc * 64 + ni * 16 + (lane & 15);
#pragma unroll
      for (int r = 0; r < 4; ++r) {
        int rowg = mt * 128 + wr * 64 + mi * 16 + (lane >> 4) * 4 + r;
        mp[(size_t)rowg * C_ + col] = acc[mi][ni][r];
      }
    }
}

__global__ __launch_bounds__(256) void k_reduce_fb(const float* __restrict__ mpart,
                                                   float* __restrict__ mfull,
                                                   int ksplit) {
  size_t i = (size_t)blockIdx.x * 256 + threadIdx.x;
  float s = 0.f;
  for (int k = 0; k < ksplit; ++k) s += mpart[(size_t)k * (B_ * C_ * C_) + i];
  mfull[i] = s;
}

__global__ __launch_bounds__(256) void k_gemm2_fb(const float* __restrict__ x,
                                                  const float* __restrict__ mat,
                                                  const float* __restrict__ inv,
                                                  const float* __restrict__ csum,
                                                  const float* __restrict__ tail,
                                                  const float* __restrict__ gamma,
                                                  float* __restrict__ out) {
  __shared__ short As[128 * 40];
  __shared__ short Bs[128 * 40];
  int bid = blockIdx.x;
  int nt = bid & 127; bid >>= 7;
  int mt = bid & 3; bid >>= 2;
  int b = bid;
  int t = threadIdx.x, lane = t & 63, w = t >> 6, wr = w >> 1, wc = w & 1;
  int srow = t >> 1, skh = t & 1;
  const float* gA = mat + ((size_t)b * C_ + mt * 128 + srow) * C_ + skh * 16;
  int kb = t >> 5, cbl = t & 31;
  int k0l = kb * 4, n0 = cbl * 4;
  const float* xb = x + (size_t)b * C_ * N_;
  const float* gB = xb + (size_t)k0l * N_ + nt * 128 + n0;
  f32x4 ivn = *(const f32x4*)(inv + b * N_ + nt * 128 + n0);
  f32x4 acc[4][4];
#pragma unroll
  for (int i = 0; i < 4; ++i)
#pragma unroll
    for (int j = 0; j < 4; ++j) acc[i][j] = f32x4{0.f, 0.f, 0.f, 0.f};
  int ldsw = srow * 40 + skh * 16;
  int lra = (wr * 64 + (lane & 15)) * 40 + (lane >> 4) * 8;
  int lrb = (wc * 64 + (lane & 15)) * 40 + (lane >> 4) * 8;
  for (int kk = 0; kk < C_; kk += 32) {
    __syncthreads();
    {
      f32x4 a0 = *(const f32x4*)(gA + kk), a1 = *(const f32x4*)(gA + kk + 4);
      f32x4 a2 = *(const f32x4*)(gA + kk + 8), a3 = *(const f32x4*)(gA + kk + 12);
      *(s16x8*)&As[ldsw] = pack8(a0, a1);
      *(s16x8*)&As[ldsw + 8] = pack8(a2, a3);
      const float* pB = gB + (size_t)kk * N_;
      f32x4 v0 = *(const f32x4*)(pB);
      f32x4 v1 = *(const f32x4*)(pB + N_);
      f32x4 v2 = *(const f32x4*)(pB + 2 * N_);
      f32x4 v3 = *(const f32x4*)(pB + 3 * N_);
#pragma unroll
      for (int cc = 0; cc < 4; ++cc) {
        s16x4 q;
        q[0] = f2bf(v0[cc] * ivn[cc]);
        q[1] = f2bf(v1[cc] * ivn[cc]);
        q[2] = f2bf(v2[cc] * ivn[cc]);
        q[3] = f2bf(v3[cc] * ivn[cc]);
        *(s16x4*)&Bs[(n0 + cc) * 40 + k0l] = q;
      }
    }
    __syncthreads();
    s16x8 af[4], bf[4];
#pragma unroll
    for (int mi = 0; mi < 4; ++mi) af[mi] = *(const s16x8*)&As[lra + mi * 16 * 40];
#pragma unroll
    for (int ni = 0; ni < 4; ++ni) bf[ni] = *(const s16x8*)&Bs[lrb + ni * 16 * 40];
#pragma unroll
    for (int mi = 0; mi < 4; ++mi)
#pragma unroll
      for (int ni = 0; ni < 4; ++ni) mfma16(acc[mi][ni], af[mi], bf[ni]);
  }
  asm volatile("s_nop 7\n\ts_nop 7\n\ts_nop 7" ::);
  float g = gamma[0];
#pragma unroll
  for (int mi = 0; mi < 4; ++mi)
#pragma unroll
    for (int ni = 0; ni < 4; ++ni) {
      int coln = nt * 128 + wc * 64 + ni * 16 + (lane & 15);
      float vs = csum[b * N_ + coln];
#pragma unroll
      for (int r = 0; r < 4; ++r) {
        int rowg = mt * 128 + wr * 64 + mi * 16 + (lane >> 4) * 4 + r;
        float ts = tail[b * C_ + rowg];
        size_t off = ((size_t)b * C_ + rowg) * N_ + coln;
        out[off] = x[off] + g * ((vs + acc[mi][ni][r]) * ts);
      }
    }
}

// ---------------------------------------------------------------------------
extern "C" void kernel_launch(void* const* d_in, const int* in_sizes, int n_in,
                              void* d_out, int out_size, void* d_ws, size_t ws_size,
                              hipStream_t stream) {
  const float* x = (const float*)d_in[0];
  const float* gamma = (const float*)d_in[1];
  float* out = (float*)d_out;
  float* wsf = (float*)d_ws;

  // Tier A ws layout (floats): csum[131072] norm[131072] tail[4096]
  //   matF[1048576 slots = 2M bf16] QnT[33554432 slots = 64M bf16]
  const size_t needA = 139476992ull;
  if (ws_size >= needA) {
    float* csum = wsf;
    float* normv = wsf + 131072;
    float* tail = wsf + 262144;
    short* matF = (short*)(wsf + 266240);
    short* QnT = (short*)(wsf + 1314816);
    // d_out scratch: W bf16 [0,128MB) | matP fp32 [128MB,170MB) | tpart [208MB,212MB)
    short* W = (short*)d_out;
    float* matP = (float*)d_out + 33554432ull;
    float* tpart = (float*)d_out + 54525952ull;

    k_prep5<<<2048, 512, 0, stream>>>(x, csum, normv, W, QnT, tpart);
    k_tailor2<<<16, 256, 0, stream>>>(tpart, tail);
    k_gemm1<<<B_ * NTILES1 * KSPLIT1, 256, 0, stream>>>(W, matP);
    k_redsum2<<<(B_ * NTILES1 * 16384) / 256, 256, 0, stream>>>(matP, matF);
    k_gemm2<<<4096, 512, 0, stream>>>(matF, QnT, csum, normv, tail, gamma, out);
  } else {
    // Tier B: round-1 proven path
    float* inv = wsf;
    float* csum = wsf + 131072;
    float* tail = wsf + 262144;
    float* matP = wsf + 266240;
    int ksplit = (ws_size >= 43008000ull) ? 4 : 1;
    float* matF = (ksplit > 1) ? (matP + (size_t)ksplit * 2097152) : matP;

    k_stats<<<512, 256, 0, stream>>>(x, inv, csum);
    k_tailor_fb<<<B_ * C_, 256, 0, stream>>>(x, inv, csum, tail);
    k_gemm1_fb<<<B_ * 16 * ksplit, 256, 0, stream>>>(x, inv, matP, ksplit);
    if (ksplit > 1) k_reduce_fb<<<8192, 256, 0, stream>>>(matP, matF, ksplit);
    k_gemm2_fb<<<B_ * 4 * 128, 256, 0, stream>>>(x, matF, inv, csum, tail, gamma, out);
  }
}